// Round 13
// baseline (293.712 us; speedup 1.0000x reference)
//
#include <hip/hip_runtime.h>
#include <math.h>

#define NN 20000
#define EE 100000
#define GG 64
#define KP 32  // padded adjacency slots per node

typedef __attribute__((ext_vector_type(8))) short short8;
typedef __attribute__((ext_vector_type(8))) unsigned short us8;
typedef __attribute__((ext_vector_type(4))) float v4f;

__device__ __forceinline__ unsigned short f2bf(float f) {
  union { float f; unsigned u; } v;
  v.f = f;
  unsigned r = v.u + 0x7fff + ((v.u >> 16) & 1);  // RNE
  return (unsigned short)(r >> 16);
}
__device__ __forceinline__ float bf2f(unsigned short s) {
  union { unsigned u; float f; } v;
  v.u = ((unsigned)s) << 16;
  return v.f;
}
__device__ __forceinline__ unsigned fenc(float x) {
  unsigned u = __float_as_uint(x);
  return (u & 0x80000000u) ? ~u : (u | 0x80000000u);
}
__device__ __forceinline__ float fdec(unsigned u) {
  unsigned b = (u & 0x80000000u) ? (u ^ 0x80000000u) : ~u;
  return __uint_as_float(b);
}

// direct global->LDS 16B load (int->AS-ptr casts; generic LDS addr low 32 bits == AS3 offset)
__device__ __forceinline__ void g2lds16(const unsigned short* g, unsigned short* l) {
  auto gp = reinterpret_cast<const __attribute__((address_space(1))) unsigned int*>(
      reinterpret_cast<uintptr_t>(g));
  auto lp = reinterpret_cast<__attribute__((address_space(3))) unsigned int*>(
      reinterpret_cast<uintptr_t>(l));
  __builtin_amdgcn_global_load_lds(gp, lp, 16, 0, 0);
}

// ---------------------------------------------------------------- prep (one dispatch)
__global__ void prep_kernel(const float* __restrict__ WA, const float* __restrict__ WB,
                            const float* __restrict__ WC, const float* __restrict__ WD,
                            const float* __restrict__ bA, const float* __restrict__ bB,
                            const float* __restrict__ bC, const float* __restrict__ bD,
                            const float* __restrict__ W2, const float* __restrict__ W3,
                            const float* __restrict__ x0, const float* __restrict__ x1,
                            unsigned short* __restrict__ Wt1, unsigned short* __restrict__ W2t,
                            unsigned short* __restrict__ W3t, float* __restrict__ bcat,
                            float* __restrict__ Psum, unsigned* __restrict__ Pmax,
                            int* __restrict__ cnt, unsigned short* __restrict__ xbf,
                            int N2, int xhalf) {
  int i = blockIdx.x * blockDim.x + threadIdx.x;
  if (i < xhalf) { xbf[i] = f2bf(x0[i]); return; }
  if (i < 2 * xhalf) { xbf[i] = f2bf(x1[i - xhalf]); return; }
  i -= 2 * xhalf;
  if (i < 512) {
    int X = i >> 7, j = i & 127;
    const float* b = (X == 0) ? bA : (X == 1) ? bB : (X == 2) ? bC : bD;
    bcat[i] = b[j];
  }
  if (i < 65536) {  // Wt1[col][k] = W1X[k][j], col = X*128+j
    int col = i >> 7, k = i & 127;
    int X = col >> 7, j = col & 127;
    const float* W = (X == 0) ? WA : (X == 1) ? WB : (X == 2) ? WC : WD;
    Wt1[col * 128 + k] = f2bf(W[k * 128 + j]);
    return;
  }
  i -= 65536;
  if (i < 131072) {  // W2t[n][k] = W2[k][n]
    int n = i >> 9, k = i & 511;
    W2t[n * 512 + k] = f2bf(W2[(size_t)k * 256 + n]);
    return;
  }
  i -= 131072;
  if (i < 32768) {  // W3t[n][k] = W3[k][n]
    int n = i >> 8, k = i & 255;
    W3t[n * 256 + k] = f2bf(W3[(size_t)k * 128 + n]);
    return;
  }
  i -= 32768;
  if (i < 16384) {
    Psum[i] = 0.f;
    Pmax[i] = 0u;
    return;
  }
  i -= 16384;
  if (i < N2) cnt[i] = 0;
}

// ---------------------------------------------------------------- padded adjacency fill
// Writes source row AND the edge's ea float4 directly into padded slots (no adje indirection).
__global__ void fill_adj(const int* __restrict__ ei0, const int* __restrict__ ei1,
                         const float* __restrict__ ea0, const float* __restrict__ ea1,
                         int* __restrict__ cnt, int* __restrict__ adjr,
                         float4* __restrict__ eaP, int E, int N) {
  int idx = blockIdx.x * blockDim.x + threadIdx.x;
  if (idx >= 2 * E) return;
  int t = idx >= E;
  int e = idx - t * E;
  const int* ei = t ? ei1 : ei0;
  const float* ea = t ? ea1 : ea0;
  int c = ei[E + e];
  int gn = t * N + c;
  int pos = atomicAdd(&cnt[gn], 1);
  if (pos < KP) {
    adjr[gn * KP + pos] = t * N + ei[e];
    eaP[gn * KP + pos] = *(const float4*)(ea + 4 * (size_t)e);
  }
}

// ---------------------------------------------------------------- degrees (sequential eaP reads)
__global__ void deg_adj(const float4* __restrict__ eaP, const int* __restrict__ cnt,
                        float* __restrict__ dis, int N) {
  int gn = blockIdx.x * blockDim.x + threadIdx.x;
  if (gn >= 2 * N) return;
  int t = gn >= N;
  int n = gn - t * N;
  int d = cnt[gn];
  if (d > KP) d = KP;
  float s0 = 1.f, s1 = 1.f, s2 = 1.f, s3 = 1.f;  // self loop
  for (int j = 0; j < d; ++j) {
    float4 w = eaP[gn * KP + j];
    s0 += w.x; s1 += w.y; s2 += w.z; s3 += w.w;
  }
  float* dg = dis + (size_t)t * 5 * N;
  dg[0 * N + n] = rsqrtf(s0);
  dg[1 * N + n] = rsqrtf(s1);
  dg[2 * N + n] = rsqrtf(s2);
  dg[3 * N + n] = rsqrtf(s3);
  dg[4 * N + n] = rsqrtf(1.f + (float)d);
}

// ---------------------------------------------------------------- norms into padded slots
__global__ void norm_adj(const float4* __restrict__ eaP, const int* __restrict__ cnt,
                         const int* __restrict__ adjr, const float* __restrict__ dis,
                         float4* __restrict__ norm4, float* __restrict__ normc, int N) {
  int idx = blockIdx.x * blockDim.x + threadIdx.x;
  if (idx >= 2 * N * KP) return;
  int gn = idx >> 5, j = idx & (KP - 1);
  int d = cnt[gn];
  if (j >= d || j >= KP) return;
  int t = gn >= N;
  int c = gn - t * N;
  const float* dg = dis + (size_t)t * 5 * N;
  int r = adjr[idx] - t * N;
  float4 w = eaP[idx];
  float4 o;
  o.x = dg[0 * N + r] * w.x * dg[0 * N + c];
  o.y = dg[1 * N + r] * w.y * dg[1 * N + c];
  o.z = dg[2 * N + r] * w.z * dg[2 * N + c];
  o.w = dg[3 * N + r] * w.w * dg[3 * N + c];
  norm4[idx] = o;
  normc[idx] = dg[4 * N + r] * dg[4 * N + c];
}

// ---------------------------------------------------------------- layer-1 aggregation of x (4 planes)
__global__ __launch_bounds__(128) void gather4(const unsigned short* __restrict__ X,
                                               const int* __restrict__ adjr,
                                               const int* __restrict__ cnt,
                                               const float4* __restrict__ norm4,
                                               const float* __restrict__ dis,
                                               unsigned short* __restrict__ Y, int N) {
  int tid = threadIdx.x;
  int gn = blockIdx.x * 8 + (tid >> 4);  // 16 threads/node
  if (gn >= 2 * N) return;
  int t = gn >= N;
  int n = gn - t * N;
  int fq = (tid & 15) << 3;
  const float* dg = dis + (size_t)t * 5 * N;
  us8 xs = *(const us8*)(X + (size_t)gn * 128 + fq);
  float xf[8];
#pragma unroll
  for (int j = 0; j < 8; ++j) xf[j] = bf2f(xs[j]);
  float acc[4][8];
#pragma unroll
  for (int p = 0; p < 4; ++p) {
    float d = dg[p * N + n];
    float dd = d * d;
#pragma unroll
    for (int j = 0; j < 8; ++j) acc[p][j] = dd * xf[j];
  }
  int deg = cnt[gn];
  if (deg > KP) deg = KP;
  int base = gn * KP;
  int i = 0;
  for (; i + 3 < deg; i += 4) {
    int r0 = adjr[base + i], r1 = adjr[base + i + 1];
    int r2 = adjr[base + i + 2], r3 = adjr[base + i + 3];
    float4 w0 = norm4[base + i], w1 = norm4[base + i + 1];
    float4 w2 = norm4[base + i + 2], w3 = norm4[base + i + 3];
    us8 h0 = *(const us8*)(X + (size_t)r0 * 128 + fq);
    us8 h1 = *(const us8*)(X + (size_t)r1 * 128 + fq);
    us8 h2 = *(const us8*)(X + (size_t)r2 * 128 + fq);
    us8 h3 = *(const us8*)(X + (size_t)r3 * 128 + fq);
#pragma unroll
    for (int j = 0; j < 8; ++j) {
      float f0 = bf2f(h0[j]), f1 = bf2f(h1[j]);
      float f2 = bf2f(h2[j]), f3 = bf2f(h3[j]);
      acc[0][j] += w0.x * f0 + w1.x * f1 + w2.x * f2 + w3.x * f3;
      acc[1][j] += w0.y * f0 + w1.y * f1 + w2.y * f2 + w3.y * f3;
      acc[2][j] += w0.z * f0 + w1.z * f1 + w2.z * f2 + w3.z * f3;
      acc[3][j] += w0.w * f0 + w1.w * f1 + w2.w * f2 + w3.w * f3;
    }
  }
  for (; i < deg; ++i) {
    int r = adjr[base + i];
    float4 w = norm4[base + i];
    us8 hr = *(const us8*)(X + (size_t)r * 128 + fq);
#pragma unroll
    for (int j = 0; j < 8; ++j) {
      float h = bf2f(hr[j]);
      acc[0][j] += w.x * h;
      acc[1][j] += w.y * h;
      acc[2][j] += w.z * h;
      acc[3][j] += w.w * h;
    }
  }
#pragma unroll
  for (int p = 0; p < 4; ++p) {
    us8 o;
#pragma unroll
    for (int j = 0; j < 8; ++j) o[j] = f2bf(acc[p][j]);
    *(us8*)(Y + (size_t)gn * 512 + p * 128 + fq) = o;
  }
}

// ---------------------------------------------------------------- block-diagonal GEMM (layer 1)
__global__ __launch_bounds__(256) void gemm_diag(const unsigned short* __restrict__ A,
                                                 const unsigned short* __restrict__ Wt1,
                                                 const float* __restrict__ bias,
                                                 unsigned short* __restrict__ Cb, int M) {
  __shared__ unsigned short As[128 * 64];
  __shared__ unsigned short Bs[128 * 64];
  int tid = threadIdx.x;
  int wave = tid >> 6, lane = tid & 63;
  int quad = lane >> 4, l16 = lane & 15;
  int n0 = blockIdx.x * 128;
  int m0 = blockIdx.y * 128;
  int wm = (wave >> 1) * 64, wn = (wave & 1) * 64;
  v4f acc[4][4] = {};
  for (int k0 = 0; k0 < 128; k0 += 64) {
#pragma unroll
    for (int l = 0; l < 4; ++l) {
      int idx = tid + (l << 8);
      int row = idx >> 3, seg = idx & 7;
      int gm = m0 + row;
      if (gm >= M) gm = M - 1;
      g2lds16(A + (size_t)gm * 512 + n0 + k0 + (seg << 3), As + idx * 8);
      int gb = n0 + row;
      g2lds16(Wt1 + (size_t)gb * 128 + k0 + (seg << 3), Bs + idx * 8);
    }
    __syncthreads();
#pragma unroll
    for (int kk = 0; kk < 2; ++kk) {
      short8 af[4], bfr[4];
#pragma unroll
      for (int r = 0; r < 4; ++r)
        af[r] = *(const short8*)(As + (wm + r * 16 + l16) * 64 + kk * 32 + quad * 8);
#pragma unroll
      for (int c = 0; c < 4; ++c)
        bfr[c] = *(const short8*)(Bs + (wn + c * 16 + l16) * 64 + kk * 32 + quad * 8);
#pragma unroll
      for (int r = 0; r < 4; ++r)
#pragma unroll
        for (int c = 0; c < 4; ++c)
          acc[r][c] = __builtin_amdgcn_mfma_f32_16x16x32_bf16(af[r], bfr[c], acc[r][c], 0, 0, 0);
    }
    __syncthreads();
  }
#pragma unroll
  for (int r = 0; r < 4; ++r) {
    int row_base = m0 + wm + r * 16 + quad * 4;
#pragma unroll
    for (int j = 0; j < 4; ++j) {
      int gm = row_base + j;
      if (gm >= M) continue;
#pragma unroll
      for (int c = 0; c < 4; ++c) {
        int col = n0 + wn + c * 16 + l16;
        float v = acc[r][c][j] + bias[col];
        Cb[(size_t)gm * 512 + col] = f2bf(fmaxf(v, 0.f));
      }
    }
  }
}

// ---------------------------------------------------------------- wide GEMM for layer 2:
// block tile 128x256 (whole N), A read once.  Bs 256x64 = 32KB LDS.
__global__ __launch_bounds__(256) void gemm_l2(const unsigned short* __restrict__ A,
                                               const unsigned short* __restrict__ Bt,
                                               unsigned short* __restrict__ Cb, int M) {
  __shared__ unsigned short As[128 * 64];
  __shared__ unsigned short Bs[256 * 64];
  const int K = 512, Nc = 256;
  int tid = threadIdx.x;
  int wave = tid >> 6, lane = tid & 63;
  int quad = lane >> 4, l16 = lane & 15;
  int m0 = blockIdx.x * 128;
  int wm = (wave >> 1) * 64, wn = (wave & 1) * 128;  // wave covers 64x128
  v4f acc[4][8] = {};
  for (int k0 = 0; k0 < K; k0 += 64) {
#pragma unroll
    for (int l = 0; l < 4; ++l) {  // A tile: 128 rows x 64k
      int idx = tid + (l << 8);
      int row = idx >> 3, seg = idx & 7;
      int gm = m0 + row;
      if (gm >= M) gm = M - 1;
      g2lds16(A + (size_t)gm * K + k0 + (seg << 3), As + idx * 8);
    }
#pragma unroll
    for (int l = 0; l < 8; ++l) {  // B tile: 256 rows x 64k
      int idx = tid + (l << 8);
      int row = idx >> 3, seg = idx & 7;
      g2lds16(Bt + (size_t)row * K + k0 + (seg << 3), Bs + idx * 8);
    }
    __syncthreads();
#pragma unroll
    for (int kk = 0; kk < 2; ++kk) {
      short8 af[4], bfr[8];
#pragma unroll
      for (int r = 0; r < 4; ++r)
        af[r] = *(const short8*)(As + (wm + r * 16 + l16) * 64 + kk * 32 + quad * 8);
#pragma unroll
      for (int c = 0; c < 8; ++c)
        bfr[c] = *(const short8*)(Bs + (wn + c * 16 + l16) * 64 + kk * 32 + quad * 8);
#pragma unroll
      for (int r = 0; r < 4; ++r)
#pragma unroll
        for (int c = 0; c < 8; ++c)
          acc[r][c] = __builtin_amdgcn_mfma_f32_16x16x32_bf16(af[r], bfr[c], acc[r][c], 0, 0, 0);
    }
    __syncthreads();
  }
#pragma unroll
  for (int r = 0; r < 4; ++r) {
    int row_base = m0 + wm + r * 16 + quad * 4;
#pragma unroll
    for (int j = 0; j < 4; ++j) {
      int gm = row_base + j;
      if (gm >= M) continue;
      unsigned short* cp = Cb + (size_t)gm * Nc + wn;
#pragma unroll
      for (int c = 0; c < 8; ++c) cp[c * 16 + l16] = f2bf(acc[r][c][j]);
    }
  }
}

// ---------------------------------------------------------------- layer-3 GEMM (Nc=128)
__global__ __launch_bounds__(256) void gemm_mfma(const unsigned short* __restrict__ A,
                                                 const unsigned short* __restrict__ Bt,
                                                 unsigned short* __restrict__ Cb,
                                                 int M, int N, int K) {
  __shared__ unsigned short As[128 * 64];
  __shared__ unsigned short Bs[128 * 64];
  int tid = threadIdx.x;
  int wave = tid >> 6, lane = tid & 63;
  int quad = lane >> 4, l16 = lane & 15;
  int m0 = blockIdx.y * 128, n0 = blockIdx.x * 128;
  int wm = (wave >> 1) * 64, wn = (wave & 1) * 64;
  v4f acc[4][4] = {};
  for (int k0 = 0; k0 < K; k0 += 64) {
#pragma unroll
    for (int l = 0; l < 4; ++l) {
      int idx = tid + (l << 8);
      int row = idx >> 3, seg = idx & 7;
      int gm = m0 + row;
      if (gm >= M) gm = M - 1;
      g2lds16(A + (size_t)gm * K + k0 + (seg << 3), As + idx * 8);
      int gn = n0 + row;
      g2lds16(Bt + (size_t)gn * K + k0 + (seg << 3), Bs + idx * 8);
    }
    __syncthreads();
#pragma unroll
    for (int kk = 0; kk < 2; ++kk) {
      short8 af[4], bfr[4];
#pragma unroll
      for (int r = 0; r < 4; ++r)
        af[r] = *(const short8*)(As + (wm + r * 16 + l16) * 64 + kk * 32 + quad * 8);
#pragma unroll
      for (int c = 0; c < 4; ++c)
        bfr[c] = *(const short8*)(Bs + (wn + c * 16 + l16) * 64 + kk * 32 + quad * 8);
#pragma unroll
      for (int r = 0; r < 4; ++r)
#pragma unroll
        for (int c = 0; c < 4; ++c)
          acc[r][c] = __builtin_amdgcn_mfma_f32_16x16x32_bf16(af[r], bfr[c], acc[r][c], 0, 0, 0);
    }
    __syncthreads();
  }
#pragma unroll
  for (int r = 0; r < 4; ++r) {
    int row_base = m0 + wm + r * 16 + quad * 4;
#pragma unroll
    for (int j = 0; j < 4; ++j) {
      int gm = row_base + j;
      if (gm >= M) continue;
      unsigned short* cp = Cb + (size_t)gm * N + n0 + wn;
#pragma unroll
      for (int c = 0; c < 4; ++c) cp[c * 16 + l16] = f2bf(acc[r][c][j]);
    }
  }
}

// ---------------------------------------------------------------- layer-2 aggregation (plane-4)
__global__ __launch_bounds__(128) void agg_gather_b(const unsigned short* __restrict__ H,
                                                    const int* __restrict__ adjr,
                                                    const int* __restrict__ cnt,
                                                    const float* __restrict__ normc,
                                                    const float* __restrict__ dis,
                                                    const float* __restrict__ bias,
                                                    unsigned short* __restrict__ OutB,
                                                    int N, int F) {
  int per8 = F >> 3;
  int tid = threadIdx.x;
  int gn = blockIdx.x * (128 / per8) + tid / per8;
  if (gn >= 2 * N) return;
  int t = gn >= N;
  int n = gn - t * N;
  int fq = (tid % per8) << 3;
  float d = dis[(size_t)(t * 5 + 4) * N + n];
  float dd = d * d;
  us8 hs = *(const us8*)(H + (size_t)gn * F + fq);
  float acc[8];
#pragma unroll
  for (int i = 0; i < 8; ++i) acc[i] = dd * bf2f(hs[i]) + bias[fq + i];
  int deg = cnt[gn];
  if (deg > KP) deg = KP;
  int base = gn * KP;
  int i = 0;
  for (; i + 3 < deg; i += 4) {
    int r0 = adjr[base + i], r1 = adjr[base + i + 1];
    int r2 = adjr[base + i + 2], r3 = adjr[base + i + 3];
    float n0 = normc[base + i], n1 = normc[base + i + 1];
    float n2 = normc[base + i + 2], n3 = normc[base + i + 3];
    us8 h0 = *(const us8*)(H + (size_t)r0 * F + fq);
    us8 h1 = *(const us8*)(H + (size_t)r1 * F + fq);
    us8 h2 = *(const us8*)(H + (size_t)r2 * F + fq);
    us8 h3 = *(const us8*)(H + (size_t)r3 * F + fq);
#pragma unroll
    for (int j = 0; j < 8; ++j)
      acc[j] += n0 * bf2f(h0[j]) + n1 * bf2f(h1[j]) + n2 * bf2f(h2[j]) + n3 * bf2f(h3[j]);
  }
  for (; i < deg; ++i) {
    int r = adjr[base + i];
    float nv = normc[base + i];
    us8 hr = *(const us8*)(H + (size_t)r * F + fq);
#pragma unroll
    for (int j = 0; j < 8; ++j) acc[j] += nv * bf2f(hr[j]);
  }
  us8 o;
#pragma unroll
  for (int i2 = 0; i2 < 8; ++i2) o[i2] = f2bf(fmaxf(acc[i2], 0.f));
  *(us8*)(OutB + (size_t)gn * F + fq) = o;
}

// ---------------------------------------------------------------- fused layer-3 agg + pool partial
__global__ __launch_bounds__(256) void agg3_pool(const unsigned short* __restrict__ H,
                                                 const int* __restrict__ adjr,
                                                 const int* __restrict__ cnt,
                                                 const float* __restrict__ normc,
                                                 const float* __restrict__ dis,
                                                 const float* __restrict__ bias,
                                                 const int* __restrict__ batch0,
                                                 const int* __restrict__ batch1,
                                                 float* __restrict__ Psum,
                                                 unsigned* __restrict__ Pmax, int N) {
  __shared__ float sS[16 * 128];
  __shared__ int bg[16];
  int tid = threadIdx.x;
  int nl = tid >> 4;
  int gn = blockIdx.x * 16 + nl;
  int fq = (tid & 15) << 3;
  if (tid < 16) {
    int g2 = blockIdx.x * 16 + tid;
    bg[tid] = (g2 < N) ? batch0[g2] : 64 + batch1[g2 - N];
  }
  int t = gn >= N;
  int n = gn - t * N;
  float d = dis[(size_t)(t * 5 + 4) * N + n];
  float dd = d * d;
  us8 hs = *(const us8*)(H + (size_t)gn * 128 + fq);
  float acc[8];
#pragma unroll
  for (int i = 0; i < 8; ++i) acc[i] = dd * bf2f(hs[i]) + bias[fq + i];
  int deg = cnt[gn];
  if (deg > KP) deg = KP;
  int base = gn * KP;
  int i = 0;
  for (; i + 3 < deg; i += 4) {
    int r0 = adjr[base + i], r1 = adjr[base + i + 1];
    int r2 = adjr[base + i + 2], r3 = adjr[base + i + 3];
    float n0 = normc[base + i], n1 = normc[base + i + 1];
    float n2 = normc[base + i + 2], n3 = normc[base + i + 3];
    us8 h0 = *(const us8*)(H + (size_t)r0 * 128 + fq);
    us8 h1 = *(const us8*)(H + (size_t)r1 * 128 + fq);
    us8 h2 = *(const us8*)(H + (size_t)r2 * 128 + fq);
    us8 h3 = *(const us8*)(H + (size_t)r3 * 128 + fq);
#pragma unroll
    for (int j = 0; j < 8; ++j)
      acc[j] += n0 * bf2f(h0[j]) + n1 * bf2f(h1[j]) + n2 * bf2f(h2[j]) + n3 * bf2f(h3[j]);
  }
  for (; i < deg; ++i) {
    int r = adjr[base + i];
    float nv = normc[base + i];
    us8 hr = *(const us8*)(H + (size_t)r * 128 + fq);
#pragma unroll
    for (int j = 0; j < 8; ++j) acc[j] += nv * bf2f(hr[j]);
  }
#pragma unroll
  for (int j = 0; j < 8; ++j) sS[nl * 128 + fq + j] = acc[j];
  __syncthreads();
  int f = tid;
  if (f >= 128) return;
  int cur = bg[0];
  float sum = 0.f, mx = -3.4e38f;
  for (int k = 0; k < 16; ++k) {
    int g = bg[k];
    if (g != cur) {
      atomicAdd(&Psum[cur * 128 + f], sum);
      atomicMax(&Pmax[cur * 128 + f], fenc(mx));
      sum = 0.f;
      mx = -3.4e38f;
      cur = g;
    }
    float v = sS[k * 128 + f];
    sum += v;
    mx = fmaxf(mx, v);
  }
  atomicAdd(&Psum[cur * 128 + f], sum);
  atomicMax(&Pmax[cur * 128 + f], fenc(mx));
}

// ---------------------------------------------------------------- fused pool-final + MLP
__device__ __forceinline__ int lower_bound_i(const int* a, int n, int key) {
  int lo = 0, hi = n;
  while (lo < hi) {
    int mid = (lo + hi) >> 1;
    if (a[mid] < key) lo = mid + 1; else hi = mid;
  }
  return lo;
}

__global__ __launch_bounds__(128) void poolmlp_kernel(const int* __restrict__ batch0,
                                                      const int* __restrict__ batch1,
                                                      const float* __restrict__ Psum,
                                                      const unsigned* __restrict__ Pmax,
                                                      const float* __restrict__ Wm1,
                                                      const float* __restrict__ bm1,
                                                      const float* __restrict__ Wm2,
                                                      const float* __restrict__ bm2,
                                                      float* __restrict__ out, int N) {
  __shared__ float sP[512];
  __shared__ float h8[8];
  int g = blockIdx.x;
  int f = threadIdx.x;
  {
    int s = lower_bound_i(batch0, N, g);
    int e = lower_bound_i(batch0, N, g + 1);
    int cnt = e - s;
    sP[f] = (cnt > 0) ? Psum[g * 128 + f] / (float)cnt : 0.f;
    sP[128 + f] = (cnt > 0) ? fdec(Pmax[g * 128 + f]) : 0.f;
  }
  {
    int s = lower_bound_i(batch1, N, g);
    int e = lower_bound_i(batch1, N, g + 1);
    int cnt = e - s;
    sP[256 + f] = (cnt > 0) ? Psum[(64 + g) * 128 + f] / (float)cnt : 0.f;
    sP[384 + f] = (cnt > 0) ? fdec(Pmax[(64 + g) * 128 + f]) : 0.f;
  }
  __syncthreads();
  if (f < 8) {
    float s = bm1[f];
    for (int k = 0; k < 512; ++k) s += sP[k] * Wm1[k * 8 + f];
    h8[f] = fmaxf(s, 0.f);
  }
  __syncthreads();
  if (f < 2) {
    float s = bm2[f];
#pragma unroll
    for (int t = 0; t < 8; ++t) s += h8[t] * Wm2[t * 2 + f];
    out[g * 2 + f] = s;
  }
}

// ---------------------------------------------------------------- launch
extern "C" void kernel_launch(void* const* d_in, const int* in_sizes, int n_in,
                              void* d_out, int out_size, void* d_ws, size_t ws_size,
                              hipStream_t stream) {
  const int N = NN, E = EE;
  const int N2 = 2 * N, E2 = 2 * E;
  float* ws = (float*)d_ws;

  // ---- workspace layout (float units)
  size_t o_bcat = 0;                          // 512
  size_t o_dis = o_bcat + 512;                // 10N
  size_t o_Psum = o_dis + 10 * (size_t)N;     // 128*128
  size_t o_Pmax = o_Psum + 128 * 128;         // 128*128 uint
  size_t o_n4 = ((o_Pmax + 128 * 128) + 3) & ~(size_t)3;  // norm4: N2*KP float4
  size_t o_ea = o_n4 + 4 * (size_t)N2 * KP;   // eaP: N2*KP float4
  size_t o_nc = o_ea + 4 * (size_t)N2 * KP;   // normc: N2*KP floats
  size_t o_int = o_nc + (size_t)N2 * KP;      // cnt[N2], adjr[N2*KP]
  size_t int_count = (size_t)N2 + (size_t)N2 * KP;
  size_t o_bf = (o_int + int_count + 7) & ~(size_t)7;

  float* bcat = ws + o_bcat;
  float* dis = ws + o_dis;
  float* Psum = ws + o_Psum;
  unsigned* Pmax = (unsigned*)(ws + o_Pmax);
  float4* norm4 = (float4*)(ws + o_n4);
  float4* eaP = (float4*)(ws + o_ea);
  float* normc = ws + o_nc;
  int* cnt = (int*)(ws + o_int);
  int* adjr = cnt + N2;
  unsigned short* bfb = (unsigned short*)(ws + o_bf);
  unsigned short* Wt1 = bfb;                      // 512*128
  unsigned short* W2t = Wt1 + 512 * 128;          // 256*512
  unsigned short* W3t = W2t + 256 * 512;          // 128*256
  unsigned short* xbf = W3t + 128 * 256;          // 2N*128
  unsigned short* Ybf = xbf + (size_t)N2 * 128;   // 2N*512
  unsigned short* Gbf = Ybf + (size_t)N2 * 512;   // 2N*512
  unsigned short* Hbf = Gbf + (size_t)N2 * 512;   // 2N*256

  const float* b2 = (const float*)d_in[17];
  const float* b3 = (const float*)d_in[19];
  const float* ea0 = (const float*)d_in[1];
  const int* ei0 = (const int*)d_in[2];
  const float* ea1 = (const float*)d_in[4];
  const int* ei1 = (const int*)d_in[5];
  const int* batch0 = (const int*)d_in[6];
  const int* batch1 = (const int*)d_in[7];

  // ---- prep
  {
    int xhalf = N * 128;
    int total = 2 * xhalf + 65536 + 131072 + 32768 + 16384 + N2;
    prep_kernel<<<(total + 255) / 256, 256, 0, stream>>>(
        (const float*)d_in[8], (const float*)d_in[10], (const float*)d_in[12],
        (const float*)d_in[14], (const float*)d_in[9], (const float*)d_in[11],
        (const float*)d_in[13], (const float*)d_in[15], (const float*)d_in[16],
        (const float*)d_in[18], (const float*)d_in[0], (const float*)d_in[3],
        Wt1, W2t, W3t, bcat, Psum, Pmax, cnt, xbf, N2, xhalf);
  }

  // ---- adjacency + degrees + norms
  fill_adj<<<(E2 + 255) / 256, 256, 0, stream>>>(ei0, ei1, ea0, ea1, cnt, adjr, eaP, E, N);
  deg_adj<<<(N2 + 255) / 256, 256, 0, stream>>>(eaP, cnt, dis, N);
  norm_adj<<<(N2 * KP + 255) / 256, 256, 0, stream>>>(eaP, cnt, adjr, dis, norm4, normc, N);

  // ---- layer 1
  gather4<<<(N2 + 7) / 8, 128, 0, stream>>>(xbf, adjr, cnt, norm4, dis, Ybf, N);
  {
    dim3 grid(4, (N2 + 127) / 128);
    gemm_diag<<<grid, 256, 0, stream>>>(Ybf, Wt1, bcat, Gbf, N2);
  }
  // ---- layer 2 (wide-tile GEMM: A read once)
  gemm_l2<<<(N2 + 127) / 128, 256, 0, stream>>>(Gbf, W2t, Hbf, N2);
  agg_gather_b<<<(N2 + 3) / 4, 128, 0, stream>>>(Hbf, adjr, cnt, normc, dis, b2, Gbf, N, 256);
  // ---- layer 3
  {
    dim3 grid(1, (N2 + 127) / 128);
    gemm_mfma<<<grid, 256, 0, stream>>>(Gbf, W3t, Hbf, N2, 128, 256);
    agg3_pool<<<N2 / 16, 256, 0, stream>>>(Hbf, adjr, cnt, normc, dis, b3, batch0, batch1,
                                           Psum, Pmax, N);
  }
  // ---- pool final + MLP
  poolmlp_kernel<<<GG, 128, 0, stream>>>(batch0, batch1, Psum, Pmax, (const float*)d_in[20],
                                         (const float*)d_in[21], (const float*)d_in[22],
                                         (const float*)d_in[23], (float*)d_out, N);
}

// Round 14
// 278.885 us; speedup vs baseline: 1.0532x; 1.0532x over previous
//
#include <hip/hip_runtime.h>
#include <math.h>

#define NN 20000
#define EE 100000
#define GG 64
#define KP 32  // padded adjacency slots per node

typedef __attribute__((ext_vector_type(8))) short short8;
typedef __attribute__((ext_vector_type(8))) unsigned short us8;
typedef __attribute__((ext_vector_type(4))) float v4f;

__device__ __forceinline__ unsigned short f2bf(float f) {
  union { float f; unsigned u; } v;
  v.f = f;
  unsigned r = v.u + 0x7fff + ((v.u >> 16) & 1);  // RNE
  return (unsigned short)(r >> 16);
}
__device__ __forceinline__ float bf2f(unsigned short s) {
  union { unsigned u; float f; } v;
  v.u = ((unsigned)s) << 16;
  return v.f;
}
__device__ __forceinline__ unsigned fenc(float x) {
  unsigned u = __float_as_uint(x);
  return (u & 0x80000000u) ? ~u : (u | 0x80000000u);
}
__device__ __forceinline__ float fdec(unsigned u) {
  unsigned b = (u & 0x80000000u) ? (u ^ 0x80000000u) : ~u;
  return __uint_as_float(b);
}

// direct global->LDS 16B load (int->AS-ptr casts; generic LDS addr low 32 bits == AS3 offset)
__device__ __forceinline__ void g2lds16(const unsigned short* g, unsigned short* l) {
  auto gp = reinterpret_cast<const __attribute__((address_space(1))) unsigned int*>(
      reinterpret_cast<uintptr_t>(g));
  auto lp = reinterpret_cast<__attribute__((address_space(3))) unsigned int*>(
      reinterpret_cast<uintptr_t>(l));
  __builtin_amdgcn_global_load_lds(gp, lp, 16, 0, 0);
}

// ---------------------------------------------------------------- prep (one dispatch)
__global__ void prep_kernel(const float* __restrict__ WA, const float* __restrict__ WB,
                            const float* __restrict__ WC, const float* __restrict__ WD,
                            const float* __restrict__ bA, const float* __restrict__ bB,
                            const float* __restrict__ bC, const float* __restrict__ bD,
                            const float* __restrict__ W2, const float* __restrict__ W3,
                            const float* __restrict__ x0, const float* __restrict__ x1,
                            unsigned short* __restrict__ Wt1, unsigned short* __restrict__ W2t,
                            unsigned short* __restrict__ W3t, float* __restrict__ bcat,
                            float* __restrict__ Psum, unsigned* __restrict__ Pmax,
                            int* __restrict__ cnt, unsigned short* __restrict__ xbf,
                            int N2, int xhalf) {
  int i = blockIdx.x * blockDim.x + threadIdx.x;
  if (i < xhalf) { xbf[i] = f2bf(x0[i]); return; }
  if (i < 2 * xhalf) { xbf[i] = f2bf(x1[i - xhalf]); return; }
  i -= 2 * xhalf;
  if (i < 512) {
    int X = i >> 7, j = i & 127;
    const float* b = (X == 0) ? bA : (X == 1) ? bB : (X == 2) ? bC : bD;
    bcat[i] = b[j];
  }
  if (i < 65536) {  // Wt1[col][k] = W1X[k][j], col = X*128+j
    int col = i >> 7, k = i & 127;
    int X = col >> 7, j = col & 127;
    const float* W = (X == 0) ? WA : (X == 1) ? WB : (X == 2) ? WC : WD;
    Wt1[col * 128 + k] = f2bf(W[k * 128 + j]);
    return;
  }
  i -= 65536;
  if (i < 131072) {  // W2t[n][k] = W2[k][n]
    int n = i >> 9, k = i & 511;
    W2t[n * 512 + k] = f2bf(W2[(size_t)k * 256 + n]);
    return;
  }
  i -= 131072;
  if (i < 32768) {  // W3t[n][k] = W3[k][n]
    int n = i >> 8, k = i & 255;
    W3t[n * 256 + k] = f2bf(W3[(size_t)k * 128 + n]);
    return;
  }
  i -= 32768;
  if (i < 16384) {
    Psum[i] = 0.f;
    Pmax[i] = 0u;
    return;
  }
  i -= 16384;
  if (i < N2) cnt[i] = 0;
}

// ---------------------------------------------------------------- padded adjacency fill
// Writes source row AND the edge's ea float4 directly into padded slots (no adje indirection).
__global__ void fill_adj(const int* __restrict__ ei0, const int* __restrict__ ei1,
                         const float* __restrict__ ea0, const float* __restrict__ ea1,
                         int* __restrict__ cnt, int* __restrict__ adjr,
                         float4* __restrict__ eaP, int E, int N) {
  int idx = blockIdx.x * blockDim.x + threadIdx.x;
  if (idx >= 2 * E) return;
  int t = idx >= E;
  int e = idx - t * E;
  const int* ei = t ? ei1 : ei0;
  const float* ea = t ? ea1 : ea0;
  int c = ei[E + e];
  int gn = t * N + c;
  int pos = atomicAdd(&cnt[gn], 1);
  if (pos < KP) {
    adjr[gn * KP + pos] = t * N + ei[e];
    eaP[gn * KP + pos] = *(const float4*)(ea + 4 * (size_t)e);
  }
}

// ---------------------------------------------------------------- degrees (sequential eaP reads)
__global__ void deg_adj(const float4* __restrict__ eaP, const int* __restrict__ cnt,
                        float* __restrict__ dis, int N) {
  int gn = blockIdx.x * blockDim.x + threadIdx.x;
  if (gn >= 2 * N) return;
  int t = gn >= N;
  int n = gn - t * N;
  int d = cnt[gn];
  if (d > KP) d = KP;
  float s0 = 1.f, s1 = 1.f, s2 = 1.f, s3 = 1.f;  // self loop
  for (int j = 0; j < d; ++j) {
    float4 w = eaP[gn * KP + j];
    s0 += w.x; s1 += w.y; s2 += w.z; s3 += w.w;
  }
  float* dg = dis + (size_t)t * 5 * N;
  dg[0 * N + n] = rsqrtf(s0);
  dg[1 * N + n] = rsqrtf(s1);
  dg[2 * N + n] = rsqrtf(s2);
  dg[3 * N + n] = rsqrtf(s3);
  dg[4 * N + n] = rsqrtf(1.f + (float)d);
}

// ---------------------------------------------------------------- norms into padded slots
__global__ void norm_adj(const float4* __restrict__ eaP, const int* __restrict__ cnt,
                         const int* __restrict__ adjr, const float* __restrict__ dis,
                         float4* __restrict__ norm4, float* __restrict__ normc, int N) {
  int idx = blockIdx.x * blockDim.x + threadIdx.x;
  if (idx >= 2 * N * KP) return;
  int gn = idx >> 5, j = idx & (KP - 1);
  int d = cnt[gn];
  if (j >= d || j >= KP) return;
  int t = gn >= N;
  int c = gn - t * N;
  const float* dg = dis + (size_t)t * 5 * N;
  int r = adjr[idx] - t * N;
  float4 w = eaP[idx];
  float4 o;
  o.x = dg[0 * N + r] * w.x * dg[0 * N + c];
  o.y = dg[1 * N + r] * w.y * dg[1 * N + c];
  o.z = dg[2 * N + r] * w.z * dg[2 * N + c];
  o.w = dg[3 * N + r] * w.w * dg[3 * N + c];
  norm4[idx] = o;
  normc[idx] = dg[4 * N + r] * dg[4 * N + c];
}

// ---------------------------------------------------------------- layer-1 aggregation of x (4 planes)
__global__ __launch_bounds__(128) void gather4(const unsigned short* __restrict__ X,
                                               const int* __restrict__ adjr,
                                               const int* __restrict__ cnt,
                                               const float4* __restrict__ norm4,
                                               const float* __restrict__ dis,
                                               unsigned short* __restrict__ Y, int N) {
  int tid = threadIdx.x;
  int gn = blockIdx.x * 8 + (tid >> 4);  // 16 threads/node
  if (gn >= 2 * N) return;
  int t = gn >= N;
  int n = gn - t * N;
  int fq = (tid & 15) << 3;
  const float* dg = dis + (size_t)t * 5 * N;
  us8 xs = *(const us8*)(X + (size_t)gn * 128 + fq);
  float xf[8];
#pragma unroll
  for (int j = 0; j < 8; ++j) xf[j] = bf2f(xs[j]);
  float acc[4][8];
#pragma unroll
  for (int p = 0; p < 4; ++p) {
    float d = dg[p * N + n];
    float dd = d * d;
#pragma unroll
    for (int j = 0; j < 8; ++j) acc[p][j] = dd * xf[j];
  }
  int deg = cnt[gn];
  if (deg > KP) deg = KP;
  int base = gn * KP;
  int i = 0;
  for (; i + 3 < deg; i += 4) {
    int r0 = adjr[base + i], r1 = adjr[base + i + 1];
    int r2 = adjr[base + i + 2], r3 = adjr[base + i + 3];
    float4 w0 = norm4[base + i], w1 = norm4[base + i + 1];
    float4 w2 = norm4[base + i + 2], w3 = norm4[base + i + 3];
    us8 h0 = *(const us8*)(X + (size_t)r0 * 128 + fq);
    us8 h1 = *(const us8*)(X + (size_t)r1 * 128 + fq);
    us8 h2 = *(const us8*)(X + (size_t)r2 * 128 + fq);
    us8 h3 = *(const us8*)(X + (size_t)r3 * 128 + fq);
#pragma unroll
    for (int j = 0; j < 8; ++j) {
      float f0 = bf2f(h0[j]), f1 = bf2f(h1[j]);
      float f2 = bf2f(h2[j]), f3 = bf2f(h3[j]);
      acc[0][j] += w0.x * f0 + w1.x * f1 + w2.x * f2 + w3.x * f3;
      acc[1][j] += w0.y * f0 + w1.y * f1 + w2.y * f2 + w3.y * f3;
      acc[2][j] += w0.z * f0 + w1.z * f1 + w2.z * f2 + w3.z * f3;
      acc[3][j] += w0.w * f0 + w1.w * f1 + w2.w * f2 + w3.w * f3;
    }
  }
  for (; i < deg; ++i) {
    int r = adjr[base + i];
    float4 w = norm4[base + i];
    us8 hr = *(const us8*)(X + (size_t)r * 128 + fq);
#pragma unroll
    for (int j = 0; j < 8; ++j) {
      float h = bf2f(hr[j]);
      acc[0][j] += w.x * h;
      acc[1][j] += w.y * h;
      acc[2][j] += w.z * h;
      acc[3][j] += w.w * h;
    }
  }
#pragma unroll
  for (int p = 0; p < 4; ++p) {
    us8 o;
#pragma unroll
    for (int j = 0; j < 8; ++j) o[j] = f2bf(acc[p][j]);
    *(us8*)(Y + (size_t)gn * 512 + p * 128 + fq) = o;
  }
}

// ---------------------------------------------------------------- block-diagonal GEMM (layer 1)
__global__ __launch_bounds__(256) void gemm_diag(const unsigned short* __restrict__ A,
                                                 const unsigned short* __restrict__ Wt1,
                                                 const float* __restrict__ bias,
                                                 unsigned short* __restrict__ Cb, int M) {
  __shared__ unsigned short As[128 * 64];
  __shared__ unsigned short Bs[128 * 64];
  int tid = threadIdx.x;
  int wave = tid >> 6, lane = tid & 63;
  int quad = lane >> 4, l16 = lane & 15;
  int n0 = blockIdx.x * 128;
  int m0 = blockIdx.y * 128;
  int wm = (wave >> 1) * 64, wn = (wave & 1) * 64;
  v4f acc[4][4] = {};
  for (int k0 = 0; k0 < 128; k0 += 64) {
#pragma unroll
    for (int l = 0; l < 4; ++l) {
      int idx = tid + (l << 8);
      int row = idx >> 3, seg = idx & 7;
      int gm = m0 + row;
      if (gm >= M) gm = M - 1;
      g2lds16(A + (size_t)gm * 512 + n0 + k0 + (seg << 3), As + idx * 8);
      int gb = n0 + row;
      g2lds16(Wt1 + (size_t)gb * 128 + k0 + (seg << 3), Bs + idx * 8);
    }
    __syncthreads();
#pragma unroll
    for (int kk = 0; kk < 2; ++kk) {
      short8 af[4], bfr[4];
#pragma unroll
      for (int r = 0; r < 4; ++r)
        af[r] = *(const short8*)(As + (wm + r * 16 + l16) * 64 + kk * 32 + quad * 8);
#pragma unroll
      for (int c = 0; c < 4; ++c)
        bfr[c] = *(const short8*)(Bs + (wn + c * 16 + l16) * 64 + kk * 32 + quad * 8);
#pragma unroll
      for (int r = 0; r < 4; ++r)
#pragma unroll
        for (int c = 0; c < 4; ++c)
          acc[r][c] = __builtin_amdgcn_mfma_f32_16x16x32_bf16(af[r], bfr[c], acc[r][c], 0, 0, 0);
    }
    __syncthreads();
  }
#pragma unroll
  for (int r = 0; r < 4; ++r) {
    int row_base = m0 + wm + r * 16 + quad * 4;
#pragma unroll
    for (int j = 0; j < 4; ++j) {
      int gm = row_base + j;
      if (gm >= M) continue;
#pragma unroll
      for (int c = 0; c < 4; ++c) {
        int col = n0 + wn + c * 16 + l16;
        float v = acc[r][c][j] + bias[col];
        Cb[(size_t)gm * 512 + col] = f2bf(fmaxf(v, 0.f));
      }
    }
  }
}

// ---------------------------------------------------------------- general bf16 MFMA GEMM (layers 2/3)
// 128x128 tile, 16KB LDS, high occupancy (reverted from 128x256 wide tile: 49KB LDS +
// 2.9M bank conflicts + 6% occupancy made it the slowest dispatch — r13 post-mortem)
__global__ __launch_bounds__(256) void gemm_mfma(const unsigned short* __restrict__ A,
                                                 const unsigned short* __restrict__ Bt,
                                                 unsigned short* __restrict__ Cb,
                                                 int M, int N, int K) {
  __shared__ unsigned short As[128 * 64];
  __shared__ unsigned short Bs[128 * 64];
  int tid = threadIdx.x;
  int wave = tid >> 6, lane = tid & 63;
  int quad = lane >> 4, l16 = lane & 15;
  int m0 = blockIdx.y * 128, n0 = blockIdx.x * 128;
  int wm = (wave >> 1) * 64, wn = (wave & 1) * 64;
  v4f acc[4][4] = {};
  for (int k0 = 0; k0 < K; k0 += 64) {
#pragma unroll
    for (int l = 0; l < 4; ++l) {
      int idx = tid + (l << 8);
      int row = idx >> 3, seg = idx & 7;
      int gm = m0 + row;
      if (gm >= M) gm = M - 1;
      g2lds16(A + (size_t)gm * K + k0 + (seg << 3), As + idx * 8);
      int gn = n0 + row;  // N multiple of 128
      g2lds16(Bt + (size_t)gn * K + k0 + (seg << 3), Bs + idx * 8);
    }
    __syncthreads();
#pragma unroll
    for (int kk = 0; kk < 2; ++kk) {
      short8 af[4], bfr[4];
#pragma unroll
      for (int r = 0; r < 4; ++r)
        af[r] = *(const short8*)(As + (wm + r * 16 + l16) * 64 + kk * 32 + quad * 8);
#pragma unroll
      for (int c = 0; c < 4; ++c)
        bfr[c] = *(const short8*)(Bs + (wn + c * 16 + l16) * 64 + kk * 32 + quad * 8);
#pragma unroll
      for (int r = 0; r < 4; ++r)
#pragma unroll
        for (int c = 0; c < 4; ++c)
          acc[r][c] = __builtin_amdgcn_mfma_f32_16x16x32_bf16(af[r], bfr[c], acc[r][c], 0, 0, 0);
    }
    __syncthreads();
  }
#pragma unroll
  for (int r = 0; r < 4; ++r) {
    int row_base = m0 + wm + r * 16 + quad * 4;
#pragma unroll
    for (int j = 0; j < 4; ++j) {
      int gm = row_base + j;
      if (gm >= M) continue;
      unsigned short* cp = Cb + (size_t)gm * N + n0 + wn;
#pragma unroll
      for (int c = 0; c < 4; ++c) cp[c * 16 + l16] = f2bf(acc[r][c][j]);
    }
  }
}

// ---------------------------------------------------------------- layer-2 aggregation (plane-4)
__global__ __launch_bounds__(128) void agg_gather_b(const unsigned short* __restrict__ H,
                                                    const int* __restrict__ adjr,
                                                    const int* __restrict__ cnt,
                                                    const float* __restrict__ normc,
                                                    const float* __restrict__ dis,
                                                    const float* __restrict__ bias,
                                                    unsigned short* __restrict__ OutB,
                                                    int N, int F) {
  int per8 = F >> 3;
  int tid = threadIdx.x;
  int gn = blockIdx.x * (128 / per8) + tid / per8;
  if (gn >= 2 * N) return;
  int t = gn >= N;
  int n = gn - t * N;
  int fq = (tid % per8) << 3;
  float d = dis[(size_t)(t * 5 + 4) * N + n];
  float dd = d * d;
  us8 hs = *(const us8*)(H + (size_t)gn * F + fq);
  float acc[8];
#pragma unroll
  for (int i = 0; i < 8; ++i) acc[i] = dd * bf2f(hs[i]) + bias[fq + i];
  int deg = cnt[gn];
  if (deg > KP) deg = KP;
  int base = gn * KP;
  int i = 0;
  for (; i + 3 < deg; i += 4) {
    int r0 = adjr[base + i], r1 = adjr[base + i + 1];
    int r2 = adjr[base + i + 2], r3 = adjr[base + i + 3];
    float n0 = normc[base + i], n1 = normc[base + i + 1];
    float n2 = normc[base + i + 2], n3 = normc[base + i + 3];
    us8 h0 = *(const us8*)(H + (size_t)r0 * F + fq);
    us8 h1 = *(const us8*)(H + (size_t)r1 * F + fq);
    us8 h2 = *(const us8*)(H + (size_t)r2 * F + fq);
    us8 h3 = *(const us8*)(H + (size_t)r3 * F + fq);
#pragma unroll
    for (int j = 0; j < 8; ++j)
      acc[j] += n0 * bf2f(h0[j]) + n1 * bf2f(h1[j]) + n2 * bf2f(h2[j]) + n3 * bf2f(h3[j]);
  }
  for (; i < deg; ++i) {
    int r = adjr[base + i];
    float nv = normc[base + i];
    us8 hr = *(const us8*)(H + (size_t)r * F + fq);
#pragma unroll
    for (int j = 0; j < 8; ++j) acc[j] += nv * bf2f(hr[j]);
  }
  us8 o;
#pragma unroll
  for (int i2 = 0; i2 < 8; ++i2) o[i2] = f2bf(fmaxf(acc[i2], 0.f));
  *(us8*)(OutB + (size_t)gn * F + fq) = o;
}

// ---------------------------------------------------------------- fused layer-3 agg + pool partial
__global__ __launch_bounds__(256) void agg3_pool(const unsigned short* __restrict__ H,
                                                 const int* __restrict__ adjr,
                                                 const int* __restrict__ cnt,
                                                 const float* __restrict__ normc,
                                                 const float* __restrict__ dis,
                                                 const float* __restrict__ bias,
                                                 const int* __restrict__ batch0,
                                                 const int* __restrict__ batch1,
                                                 float* __restrict__ Psum,
                                                 unsigned* __restrict__ Pmax, int N) {
  __shared__ float sS[16 * 128];
  __shared__ int bg[16];
  int tid = threadIdx.x;
  int nl = tid >> 4;
  int gn = blockIdx.x * 16 + nl;
  int fq = (tid & 15) << 3;
  if (tid < 16) {
    int g2 = blockIdx.x * 16 + tid;
    bg[tid] = (g2 < N) ? batch0[g2] : 64 + batch1[g2 - N];
  }
  int t = gn >= N;
  int n = gn - t * N;
  float d = dis[(size_t)(t * 5 + 4) * N + n];
  float dd = d * d;
  us8 hs = *(const us8*)(H + (size_t)gn * 128 + fq);
  float acc[8];
#pragma unroll
  for (int i = 0; i < 8; ++i) acc[i] = dd * bf2f(hs[i]) + bias[fq + i];
  int deg = cnt[gn];
  if (deg > KP) deg = KP;
  int base = gn * KP;
  int i = 0;
  for (; i + 3 < deg; i += 4) {
    int r0 = adjr[base + i], r1 = adjr[base + i + 1];
    int r2 = adjr[base + i + 2], r3 = adjr[base + i + 3];
    float n0 = normc[base + i], n1 = normc[base + i + 1];
    float n2 = normc[base + i + 2], n3 = normc[base + i + 3];
    us8 h0 = *(const us8*)(H + (size_t)r0 * 128 + fq);
    us8 h1 = *(const us8*)(H + (size_t)r1 * 128 + fq);
    us8 h2 = *(const us8*)(H + (size_t)r2 * 128 + fq);
    us8 h3 = *(const us8*)(H + (size_t)r3 * 128 + fq);
#pragma unroll
    for (int j = 0; j < 8; ++j)
      acc[j] += n0 * bf2f(h0[j]) + n1 * bf2f(h1[j]) + n2 * bf2f(h2[j]) + n3 * bf2f(h3[j]);
  }
  for (; i < deg; ++i) {
    int r = adjr[base + i];
    float nv = normc[base + i];
    us8 hr = *(const us8*)(H + (size_t)r * 128 + fq);
#pragma unroll
    for (int j = 0; j < 8; ++j) acc[j] += nv * bf2f(hr[j]);
  }
#pragma unroll
  for (int j = 0; j < 8; ++j) sS[nl * 128 + fq + j] = acc[j];
  __syncthreads();
  int f = tid;
  if (f >= 128) return;
  int cur = bg[0];
  float sum = 0.f, mx = -3.4e38f;
  for (int k = 0; k < 16; ++k) {
    int g = bg[k];
    if (g != cur) {
      atomicAdd(&Psum[cur * 128 + f], sum);
      atomicMax(&Pmax[cur * 128 + f], fenc(mx));
      sum = 0.f;
      mx = -3.4e38f;
      cur = g;
    }
    float v = sS[k * 128 + f];
    sum += v;
    mx = fmaxf(mx, v);
  }
  atomicAdd(&Psum[cur * 128 + f], sum);
  atomicMax(&Pmax[cur * 128 + f], fenc(mx));
}

// ---------------------------------------------------------------- fused pool-final + MLP
__device__ __forceinline__ int lower_bound_i(const int* a, int n, int key) {
  int lo = 0, hi = n;
  while (lo < hi) {
    int mid = (lo + hi) >> 1;
    if (a[mid] < key) lo = mid + 1; else hi = mid;
  }
  return lo;
}

__global__ __launch_bounds__(128) void poolmlp_kernel(const int* __restrict__ batch0,
                                                      const int* __restrict__ batch1,
                                                      const float* __restrict__ Psum,
                                                      const unsigned* __restrict__ Pmax,
                                                      const float* __restrict__ Wm1,
                                                      const float* __restrict__ bm1,
                                                      const float* __restrict__ Wm2,
                                                      const float* __restrict__ bm2,
                                                      float* __restrict__ out, int N) {
  __shared__ float sP[512];
  __shared__ float h8[8];
  int g = blockIdx.x;
  int f = threadIdx.x;
  {
    int s = lower_bound_i(batch0, N, g);
    int e = lower_bound_i(batch0, N, g + 1);
    int cnt = e - s;
    sP[f] = (cnt > 0) ? Psum[g * 128 + f] / (float)cnt : 0.f;
    sP[128 + f] = (cnt > 0) ? fdec(Pmax[g * 128 + f]) : 0.f;
  }
  {
    int s = lower_bound_i(batch1, N, g);
    int e = lower_bound_i(batch1, N, g + 1);
    int cnt = e - s;
    sP[256 + f] = (cnt > 0) ? Psum[(64 + g) * 128 + f] / (float)cnt : 0.f;
    sP[384 + f] = (cnt > 0) ? fdec(Pmax[(64 + g) * 128 + f]) : 0.f;
  }
  __syncthreads();
  if (f < 8) {
    float s = bm1[f];
    for (int k = 0; k < 512; ++k) s += sP[k] * Wm1[k * 8 + f];
    h8[f] = fmaxf(s, 0.f);
  }
  __syncthreads();
  if (f < 2) {
    float s = bm2[f];
#pragma unroll
    for (int t = 0; t < 8; ++t) s += h8[t] * Wm2[t * 2 + f];
    out[g * 2 + f] = s;
  }
}

// ---------------------------------------------------------------- launch
extern "C" void kernel_launch(void* const* d_in, const int* in_sizes, int n_in,
                              void* d_out, int out_size, void* d_ws, size_t ws_size,
                              hipStream_t stream) {
  const int N = NN, E = EE;
  const int N2 = 2 * N, E2 = 2 * E;
  float* ws = (float*)d_ws;

  // ---- workspace layout (float units)
  size_t o_bcat = 0;                          // 512
  size_t o_dis = o_bcat + 512;                // 10N
  size_t o_Psum = o_dis + 10 * (size_t)N;     // 128*128
  size_t o_Pmax = o_Psum + 128 * 128;         // 128*128 uint
  size_t o_n4 = ((o_Pmax + 128 * 128) + 3) & ~(size_t)3;  // norm4: N2*KP float4
  size_t o_ea = o_n4 + 4 * (size_t)N2 * KP;   // eaP: N2*KP float4
  size_t o_nc = o_ea + 4 * (size_t)N2 * KP;   // normc: N2*KP floats
  size_t o_int = o_nc + (size_t)N2 * KP;      // cnt[N2], adjr[N2*KP]
  size_t int_count = (size_t)N2 + (size_t)N2 * KP;
  size_t o_bf = (o_int + int_count + 7) & ~(size_t)7;

  float* bcat = ws + o_bcat;
  float* dis = ws + o_dis;
  float* Psum = ws + o_Psum;
  unsigned* Pmax = (unsigned*)(ws + o_Pmax);
  float4* norm4 = (float4*)(ws + o_n4);
  float4* eaP = (float4*)(ws + o_ea);
  float* normc = ws + o_nc;
  int* cnt = (int*)(ws + o_int);
  int* adjr = cnt + N2;
  unsigned short* bfb = (unsigned short*)(ws + o_bf);
  unsigned short* Wt1 = bfb;                      // 512*128
  unsigned short* W2t = Wt1 + 512 * 128;          // 256*512
  unsigned short* W3t = W2t + 256 * 512;          // 128*256
  unsigned short* xbf = W3t + 128 * 256;          // 2N*128
  unsigned short* Ybf = xbf + (size_t)N2 * 128;   // 2N*512
  unsigned short* Gbf = Ybf + (size_t)N2 * 512;   // 2N*512
  unsigned short* Hbf = Gbf + (size_t)N2 * 512;   // 2N*256

  const float* b2 = (const float*)d_in[17];
  const float* b3 = (const float*)d_in[19];
  const float* ea0 = (const float*)d_in[1];
  const int* ei0 = (const int*)d_in[2];
  const float* ea1 = (const float*)d_in[4];
  const int* ei1 = (const int*)d_in[5];
  const int* batch0 = (const int*)d_in[6];
  const int* batch1 = (const int*)d_in[7];

  // ---- prep
  {
    int xhalf = N * 128;
    int total = 2 * xhalf + 65536 + 131072 + 32768 + 16384 + N2;
    prep_kernel<<<(total + 255) / 256, 256, 0, stream>>>(
        (const float*)d_in[8], (const float*)d_in[10], (const float*)d_in[12],
        (const float*)d_in[14], (const float*)d_in[9], (const float*)d_in[11],
        (const float*)d_in[13], (const float*)d_in[15], (const float*)d_in[16],
        (const float*)d_in[18], (const float*)d_in[0], (const float*)d_in[3],
        Wt1, W2t, W3t, bcat, Psum, Pmax, cnt, xbf, N2, xhalf);
  }

  // ---- adjacency + degrees + norms
  fill_adj<<<(E2 + 255) / 256, 256, 0, stream>>>(ei0, ei1, ea0, ea1, cnt, adjr, eaP, E, N);
  deg_adj<<<(N2 + 255) / 256, 256, 0, stream>>>(eaP, cnt, dis, N);
  norm_adj<<<(N2 * KP + 255) / 256, 256, 0, stream>>>(eaP, cnt, adjr, dis, norm4, normc, N);

  // ---- layer 1
  gather4<<<(N2 + 7) / 8, 128, 0, stream>>>(xbf, adjr, cnt, norm4, dis, Ybf, N);
  {
    dim3 grid(4, (N2 + 127) / 128);
    gemm_diag<<<grid, 256, 0, stream>>>(Ybf, Wt1, bcat, Gbf, N2);
  }
  // ---- layer 2 (128x128 tile, grid(2, 313))
  {
    dim3 grid(2, (N2 + 127) / 128);
    gemm_mfma<<<grid, 256, 0, stream>>>(Gbf, W2t, Hbf, N2, 256, 512);
    agg_gather_b<<<(N2 + 3) / 4, 128, 0, stream>>>(Hbf, adjr, cnt, normc, dis, b2, Gbf, N, 256);
  }
  // ---- layer 3
  {
    dim3 grid(1, (N2 + 127) / 128);
    gemm_mfma<<<grid, 256, 0, stream>>>(Gbf, W3t, Hbf, N2, 128, 256);
    agg3_pool<<<N2 / 16, 256, 0, stream>>>(Hbf, adjr, cnt, normc, dis, b3, batch0, batch1,
                                           Psum, Pmax, N);
  }
  // ---- pool final + MLP
  poolmlp_kernel<<<GG, 128, 0, stream>>>(batch0, batch1, Psum, Pmax, (const float*)d_in[20],
                                         (const float*)d_in[21], (const float*)d_in[22],
                                         (const float*)d_in[23], (float*)d_out, N);
}